// Round 8
// baseline (457.848 us; speedup 1.0000x reference)
//
#include <hip/hip_runtime.h>

// Problem constants
#define B_TOK 4096
#define HDIM 1024
#define IDIM 4096
#define NSLOT 8192          // B_TOK * TOP_K
#define MAX_T128 72         // 128-row tiles: 64 + 7 = 71 max, +1 spare

using short8   = __attribute__((ext_vector_type(8))) short;
using bf16x8   = __attribute__((ext_vector_type(8))) __bf16;
using f32x4    = __attribute__((ext_vector_type(4))) float;
using int4v    = __attribute__((ext_vector_type(4))) int;
using ushort4v = __attribute__((ext_vector_type(4))) unsigned short;
using float4v  = __attribute__((ext_vector_type(4))) float;

// meta layout (ints) — 128-granular tile table
#define MC_NT128   0
#define MC_E128    8      // 72 entries
#define MC_M0128   80     // 72
#define MC_RW128   152    // 72
#define META_INTS  256

__device__ __forceinline__ unsigned short f2bf(float f) {
  unsigned u = __float_as_uint(f);
  u += 0x7FFFu + ((u >> 16) & 1u);   // RNE
  return (unsigned short)(u >> 16);
}
__device__ __forceinline__ float bf2f(unsigned short h) {
  return __uint_as_float(((unsigned)h) << 16);
}
__device__ __forceinline__ f32x4 mfma_bf16(short8 a, short8 b, f32x4 c) {
  return __builtin_amdgcn_mfma_f32_16x16x32_bf16(
      __builtin_bit_cast(bf16x8, a), __builtin_bit_cast(bf16x8, b), c, 0, 0, 0);
}
__device__ __forceinline__ void gload16(const unsigned short* g, unsigned short* l) {
  __builtin_amdgcn_global_load_lds(
      (const __attribute__((address_space(1))) unsigned int*)g,
      (__attribute__((address_space(3))) unsigned int*)l, 16, 0, 0);
}

// One wave per token: logits = x@Wr + br + noise; top-2; softmax-of-2.
__global__ __launch_bounds__(256) void router_kernel(
    const float* __restrict__ x, const float* __restrict__ noise,
    const float* __restrict__ Wr, const float* __restrict__ br,
    int* __restrict__ idxmap, float* __restrict__ wmap) {
  int tok = blockIdx.x * 4 + (threadIdx.x >> 6);
  int l = threadIdx.x & 63;
  const float* xr = x + (size_t)tok * HDIM;
  float acc[8];
#pragma unroll
  for (int e = 0; e < 8; e++) acc[e] = 0.f;
  for (int hb = 0; hb < HDIM; hb += 256) {
    int h = hb + l * 4;
    float4v xv = *(const float4v*)(xr + h);
#pragma unroll
    for (int j = 0; j < 4; j++) {
      float4v w0 = *(const float4v*)(Wr + (size_t)(h + j) * 8);
      float4v w1 = *(const float4v*)(Wr + (size_t)(h + j) * 8 + 4);
      acc[0] += xv[j] * w0[0]; acc[1] += xv[j] * w0[1];
      acc[2] += xv[j] * w0[2]; acc[3] += xv[j] * w0[3];
      acc[4] += xv[j] * w1[0]; acc[5] += xv[j] * w1[1];
      acc[6] += xv[j] * w1[2]; acc[7] += xv[j] * w1[3];
    }
  }
#pragma unroll
  for (int off = 32; off > 0; off >>= 1) {
#pragma unroll
    for (int e = 0; e < 8; e++) acc[e] += __shfl_xor(acc[e], off, 64);
  }
  if (l == 0) {
    float y[8];
#pragma unroll
    for (int e = 0; e < 8; e++) y[e] = acc[e] + br[e] + noise[(size_t)tok * 8 + e];
    int e0 = 0;
#pragma unroll
    for (int e = 1; e < 8; e++) if (y[e] > y[e0]) e0 = e;   // ties -> lower idx
    int e1 = (e0 == 0) ? 1 : 0;
#pragma unroll
    for (int e = 0; e < 8; e++) if (e != e0 && y[e] > y[e1]) e1 = e;
    float w0 = 1.f / (1.f + __expf(y[e1] - y[e0]));          // softmax of 2
    idxmap[tok * 2] = e0; idxmap[tok * 2 + 1] = e1;
    wmap[tok * 2] = w0;   wmap[tok * 2 + 1] = 1.f - w0;
  }
}

// Deterministic slot ranks via packed prefix scan; builds 128-row tile table.
__global__ __launch_bounds__(1024) void rank_kernel(
    const int* __restrict__ idxmap, int* __restrict__ slotmap,
    int* __restrict__ meta) {
  int tid = threadIdx.x, lane = tid & 63, wv = tid >> 6;
  __shared__ unsigned wtot[16][4];
  __shared__ unsigned woff[16][4];
  __shared__ unsigned offE[8];

  int es[8];
  unsigned p0 = 0, p1 = 0, p2 = 0, p3 = 0;
#pragma unroll
  for (int j = 0; j < 8; j++) {
    int e = idxmap[tid * 8 + j];
    es[j] = e;
    unsigned c = 1u << ((e & 1) * 16);
    if (e < 2) p0 += c; else if (e < 4) p1 += c;
    else if (e < 6) p2 += c; else p3 += c;
  }
  unsigned i0 = p0, i1 = p1, i2 = p2, i3 = p3;
#pragma unroll
  for (int d = 1; d < 64; d <<= 1) {
    unsigned t0 = __shfl_up(i0, d, 64), t1 = __shfl_up(i1, d, 64);
    unsigned t2 = __shfl_up(i2, d, 64), t3 = __shfl_up(i3, d, 64);
    if (lane >= d) { i0 += t0; i1 += t1; i2 += t2; i3 += t3; }
  }
  if (lane == 63) { wtot[wv][0] = i0; wtot[wv][1] = i1; wtot[wv][2] = i2; wtot[wv][3] = i3; }
  __syncthreads();
  if (wv == 0 && lane < 16) {
    unsigned a0 = wtot[lane][0], a1 = wtot[lane][1], a2 = wtot[lane][2], a3 = wtot[lane][3];
    unsigned s0 = a0, s1 = a1, s2 = a2, s3 = a3;
#pragma unroll
    for (int d = 1; d < 16; d <<= 1) {
      unsigned t0 = __shfl_up(s0, d, 64), t1 = __shfl_up(s1, d, 64);
      unsigned t2 = __shfl_up(s2, d, 64), t3 = __shfl_up(s3, d, 64);
      if (lane >= d) { s0 += t0; s1 += t1; s2 += t2; s3 += t3; }
    }
    woff[lane][0] = s0 - a0; woff[lane][1] = s1 - a1;
    woff[lane][2] = s2 - a2; woff[lane][3] = s3 - a3;
    if (lane == 15) {
      unsigned t[8];
      t[0] = s0 & 0xFFFF; t[1] = s0 >> 16; t[2] = s1 & 0xFFFF; t[3] = s1 >> 16;
      t[4] = s2 & 0xFFFF; t[5] = s2 >> 16; t[6] = s3 & 0xFFFF; t[7] = s3 >> 16;
      unsigned off = 0; int tc = 0;
      for (int e = 0; e < 8; e++) {
        offE[e] = off;
        for (unsigned i = 0; i < t[e]; i += 128) {
          meta[MC_E128 + tc] = e;
          meta[MC_M0128 + tc] = (int)(off + i);
          meta[MC_RW128 + tc] = (int)((t[e] - i < 128u) ? (t[e] - i) : 128u);
          tc++;
        }
        off += t[e];
      }
      meta[MC_NT128] = tc;
    }
  }
  __syncthreads();
  unsigned e0w = i0 - p0 + woff[wv][0];
  unsigned e1w = i1 - p1 + woff[wv][1];
  unsigned e2w = i2 - p2 + woff[wv][2];
  unsigned e3w = i3 - p3 + woff[wv][3];
#pragma unroll
  for (int j = 0; j < 8; j++) {
    int e = es[j];
    unsigned sh = (unsigned)(e & 1) * 16;
    unsigned c = 1u << sh, v;
    if (e < 2)      { v = (e0w >> sh) & 0xFFFF; e0w += c; }
    else if (e < 4) { v = (e1w >> sh) & 0xFFFF; e1w += c; }
    else if (e < 6) { v = (e2w >> sh) & 0xFFFF; e2w += c; }
    else            { v = (e3w >> sh) & 0xFFFF; e3w += c; }
    slotmap[tid * 8 + j] = (int)(offE[e] + v);
  }
}

// Pure scatter-gather: x row (fp32) -> bf16 to both slots.
__global__ __launch_bounds__(256) void place_kernel(
    const float* __restrict__ x, const int* __restrict__ slotmap,
    unsigned short* __restrict__ x_g) {
  int tok = blockIdx.x * 2 + (threadIdx.x >> 7);
  int h = (threadIdx.x & 127) * 8;
  const float* xr = x + (size_t)tok * HDIM + h;
  float4v v0 = *(const float4v*)xr;
  float4v v1 = *(const float4v*)(xr + 4);
  int4v p;
  p[0] = (int)((unsigned)f2bf(v0[0]) | ((unsigned)f2bf(v0[1]) << 16));
  p[1] = (int)((unsigned)f2bf(v0[2]) | ((unsigned)f2bf(v0[3]) << 16));
  p[2] = (int)((unsigned)f2bf(v1[0]) | ((unsigned)f2bf(v1[1]) << 16));
  p[3] = (int)((unsigned)f2bf(v1[2]) | ((unsigned)f2bf(v1[3]) << 16));
  int s0 = slotmap[tok * 2], s1 = slotmap[tok * 2 + 1];
  *(int4v*)(x_g + (size_t)s0 * HDIM + h) = p;
  *(int4v*)(x_g + (size_t)s1 * HDIM + h) = p;
}

// W_in fp32 [8][1024][8192] -> W_in_t bf16 [e][J2(32)][256 panel-rows][1024 k]
// pr = (jj>>4)*32 + half*16 + (jj&15), jj in 0..127 (x1/x2 16-col interleave)
__global__ __launch_bounds__(256) void prep_win_kernel(
    const float* __restrict__ W_in, unsigned short* __restrict__ Wt) {
  int e = blockIdx.z, k0 = blockIdx.y * 64, n0 = blockIdx.x * 64;
  __shared__ __align__(16) unsigned short T[64 * 72];
  int tid = threadIdx.x;
#pragma unroll
  for (int i = 0; i < 4; i++) {
    int q = i * 256 + tid;
    int kr = q >> 4, nc = (q & 15) * 4;
    float4v v = *(const float4v*)(W_in + ((size_t)e * 1024 + k0 + kr) * 8192 + n0 + nc);
#pragma unroll
    for (int j = 0; j < 4; j++) T[(nc + j) * 72 + kr] = f2bf(v[j]);
  }
  __syncthreads();
  int half = (n0 >= 4096) ? 1 : 0;
  int j0 = n0 - half * 4096;
  int J2 = j0 >> 7;
  int jjb = j0 & 127;          // 0 or 64
  unsigned short* ob = Wt + (((size_t)e * 32 + J2) << 18);   // 256x1024 panel
#pragma unroll
  for (int i = 0; i < 2; i++) {
    int q = i * 256 + tid;
    int nr = q >> 3, kc = (q & 7) * 8;
    int pr = jjb * 2 + (nr >> 4) * 32 + half * 16 + (nr & 15);
    *(int4v*)(ob + (size_t)pr * 1024 + k0 + kc) = *(const int4v*)&T[nr * 72 + kc];
  }
}

// W_out fp32 [8][4096][1024] -> W_out_t bf16 [e][n=1024][k=4096]
__global__ __launch_bounds__(256) void prep_wout_kernel(
    const float* __restrict__ W_out, unsigned short* __restrict__ Wt) {
  int e = blockIdx.z, k0 = blockIdx.y * 64, n0 = blockIdx.x * 64;
  __shared__ __align__(16) unsigned short T[64 * 72];
  int tid = threadIdx.x;
#pragma unroll
  for (int i = 0; i < 4; i++) {
    int q = i * 256 + tid;
    int kr = q >> 4, nc = (q & 15) * 4;
    float4v v = *(const float4v*)(W_out + ((size_t)e * 4096 + k0 + kr) * 1024 + n0 + nc);
#pragma unroll
    for (int j = 0; j < 4; j++) T[(nc + j) * 72 + kr] = f2bf(v[j]);
  }
  __syncthreads();
  unsigned short* ob = Wt + ((size_t)e * 1024 + n0) * 4096;
#pragma unroll
  for (int i = 0; i < 2; i++) {
    int q = i * 256 + tid;
    int nr = q >> 3, kc = (q & 7) * 8;
    *(int4v*)(ob + (size_t)nr * 4096 + k0 + kc) = *(const int4v*)&T[nr * 72 + kc];
  }
}

// ---- GEMM1: 128m x 256n tile, BK=64, 4 waves (2Mx2N, wave tile 64x128),
// r7 2-phase __syncthreads structure (proven), XCD J2-banding.
// LDS 48 KB; acc[4][8] (~190 VGPR) -> 2 blocks/CU, 8 waves/CU.
// Wave-tile enlargement: 43.7 FLOP per LDS byte vs 32 at 64x64.
__global__ __launch_bounds__(256, 2) void gemm1a_kernel(
    const unsigned short* __restrict__ x_g, const unsigned short* __restrict__ Wt,
    const float* __restrict__ b_in, unsigned short* __restrict__ a_buf,
    const int* __restrict__ meta) {
  int bid = blockIdx.x;
  int xcd = bid & 7, local = bid >> 3;
  int t = local >> 2;                         // t-major within XCD chunk
  if (t >= meta[MC_NT128]) return;
  int J2 = xcd * 4 + (local & 3);             // per-XCD band of 4 panels (2 MB)
  int e = meta[MC_E128 + t];
  int m0 = meta[MC_M0128 + t];
  int rows = meta[MC_RW128 + t];
  const unsigned short* Wp = Wt + (((size_t)e * 32 + J2) << 18);

  __shared__ __align__(16) unsigned short As[128 * 64];   // 16 KB
  __shared__ __align__(16) unsigned short Bs[256 * 64];   // 32 KB

  int tid = threadIdx.x, l = tid & 63, w = tid >> 6;
  int g = l >> 4, ln = l & 15, lr = l >> 3;
  int uc = (l & 7) ^ lr;                      // pre-swizzled source 16B-unit
  int wm = w >> 1, wn = w & 1;

  const unsigned short* sA[4]; int dAo[4];
#pragma unroll
  for (int i = 0; i < 4; i++) {
    int c = w * 4 + i;                        // A chunk 0..15 (8 rows each)
    int r = c * 8 + lr;
    int ra = r < rows ? r : rows - 1;
    sA[i] = x_g + (size_t)(m0 + ra) * HDIM + uc * 8;
    dAo[i] = c * 512 + l * 8;
  }
  const unsigned short* sB[8]; int dBo[8];
#pragma unroll
  for (int i = 0; i < 8; i++) {
    int c = w * 8 + i;                        // B chunk 0..31 (8 panel-rows each)
    int r = c * 8 + lr;
    sB[i] = Wp + (size_t)r * 1024 + uc * 8;
    dBo[i] = c * 512 + l * 8;
  }

  f32x4 acc[4][8];
#pragma unroll
  for (int mf = 0; mf < 4; mf++)
#pragma unroll
    for (int nf = 0; nf < 8; nf++) acc[mf][nf] = (f32x4){0.f, 0.f, 0.f, 0.f};

#pragma unroll 1
  for (int kt = 0; kt < 16; kt++) {
#pragma unroll
    for (int i = 0; i < 4; i++) gload16(sA[i] + kt * 64, &As[dAo[i]]);
#pragma unroll
    for (int i = 0; i < 8; i++) gload16(sB[i] + kt * 64, &Bs[dBo[i]]);
    __syncthreads();
#pragma unroll
    for (int ks = 0; ks < 2; ks++) {
      int u0 = (((ks * 4 + g) ^ (ln & 7)) << 3);
      short8 af[4], bfr[8];
#pragma unroll
      for (int mf = 0; mf < 4; mf++)
        af[mf] = *(const short8*)&As[(wm * 64 + mf * 16 + ln) * 64 + u0];
#pragma unroll
      for (int nf = 0; nf < 8; nf++)
        bfr[nf] = *(const short8*)&Bs[(wn * 128 + nf * 16 + ln) * 64 + u0];
#pragma unroll
      for (int mf = 0; mf < 4; mf++)
#pragma unroll
        for (int nf = 0; nf < 8; nf++)
          acc[mf][nf] = mfma_bf16(af[mf], bfr[nf], acc[mf][nf]);
    }
    __syncthreads();
  }
  // fused bias + SwiGLU: frag pair (2p, 2p+1) = (x1, x2) of same j;
  // jj = (wn*4 + p)*16 + ln, j = J2*128 + jj   (derived from prep pr-mapping)
#pragma unroll
  for (int mf = 0; mf < 4; mf++) {
#pragma unroll
    for (int p = 0; p < 4; p++) {
      int j = J2 * 128 + (wn * 4 + p) * 16 + ln;
      float b1 = b_in[(size_t)e * 8192 + j];
      float b2 = b_in[(size_t)e * 8192 + 4096 + j];
#pragma unroll
      for (int r = 0; r < 4; r++) {
        int m = wm * 64 + mf * 16 + g * 4 + r;
        if (m < rows) {
          float h1 = acc[mf][p * 2][r] + b1;
          float h2 = acc[mf][p * 2 + 1][r] + b2;
          a_buf[(size_t)(m0 + m) * IDIM + j] = f2bf(h1 / (1.f + __expf(-h2)));
        }
      }
    }
  }
}

// ---- GEMM2: 128m x 128n tile, K=4096, 4 waves (2Mx2N, 64x64/wave), 2-phase,
// n-band = xcd (W_out 8 MB/XCD band; per-expert slab 1 MB L2-resident).
__global__ __launch_bounds__(256, 4) void gemm2a_kernel(
    const unsigned short* __restrict__ a_buf, const unsigned short* __restrict__ Wt,
    const float* __restrict__ b_out, unsigned short* __restrict__ buf2,
    const int* __restrict__ meta) {
  int bid = blockIdx.x;
  int xcd = bid & 7;
  int t = bid >> 3;
  if (t >= meta[MC_NT128]) return;
  int n0 = xcd * 128;
  int e = meta[MC_E128 + t];
  int m0 = meta[MC_M0128 + t];
  int rows = meta[MC_RW128 + t];
  const unsigned short* Wp = Wt + ((size_t)e * 1024 + n0) * 4096;

  __shared__ __align__(16) unsigned short As[128 * 64];   // 16 KB
  __shared__ __align__(16) unsigned short Bs[128 * 64];   // 16 KB

  int tid = threadIdx.x, l = tid & 63, w = tid >> 6;
  int g = l >> 4, ln = l & 15, lr = l >> 3;
  int uc = (l & 7) ^ lr;
  int wm = w >> 1, wn = w & 1;

  const unsigned short* sA[4]; const unsigned short* sB[4]; int dO[4];
#pragma unroll
  for (int i = 0; i < 4; i++) {
    int c = w * 4 + i;                        // chunk 0..15
    int r = c * 8 + lr;
    int ra = r < rows ? r : rows - 1;
    sA[i] = a_buf + (size_t)(m0 + ra) * IDIM + uc * 8;
    sB[i] = Wp + (size_t)r * 4096 + uc * 8;
    dO[i] = c * 512 + l * 8;
  }

  f32x4 acc[4][4];
#pragma unroll
  for (int mf = 0; mf < 4; mf++)
#pragma unroll
    for (int nf = 0; nf < 4; nf++) acc[mf][nf] = (f32x4){0.f, 0.f, 0.f, 0.f};

#pragma unroll 1
  for (int kt = 0; kt < 64; kt++) {
#pragma unroll
    for (int i = 0; i < 4; i++) gload16(sA[i] + kt * 64, &As[dO[i]]);
#pragma unroll
    for (int i = 0; i < 4; i++) gload16(sB[i] + kt * 64, &Bs[dO[i]]);
    __syncthreads();
#pragma unroll
    for (int ks = 0; ks < 2; ks++) {
      int u0 = (((ks * 4 + g) ^ (ln & 7)) << 3);
      short8 af[4], bfr[4];
#pragma unroll
      for (int mf = 0; mf < 4; mf++)
        af[mf] = *(const short8*)&As[(wm * 64 + mf * 16 + ln) * 64 + u0];
#pragma unroll
      for (int nf = 0; nf < 4; nf++)
        bfr[nf] = *(const short8*)&Bs[(wn * 64 + nf * 16 + ln) * 64 + u0];
#pragma unroll
      for (int mf = 0; mf < 4; mf++)
#pragma unroll
        for (int nf = 0; nf < 4; nf++)
          acc[mf][nf] = mfma_bf16(af[mf], bfr[nf], acc[mf][nf]);
    }
    __syncthreads();
  }
#pragma unroll
  for (int mf = 0; mf < 4; mf++) {
#pragma unroll
    for (int nf = 0; nf < 4; nf++) {
      int col = n0 + wn * 64 + nf * 16 + ln;
      float bo = b_out[(size_t)e * 1024 + col];
#pragma unroll
      for (int r = 0; r < 4; r++) {
        int m = wm * 64 + mf * 16 + g * 4 + r;
        if (m < rows) {
          buf2[(size_t)(m0 + m) * HDIM + col] = f2bf(acc[mf][nf][r] + bo);
        }
      }
    }
  }
}

// out[b] = w0 * buf2[slot0] + w1 * buf2[slot1]  (fp32, deterministic order)
__global__ __launch_bounds__(256) void combine_kernel(
    const unsigned short* __restrict__ buf2, const int* __restrict__ slotmap,
    const float* __restrict__ wmap, float* __restrict__ out) {
  int i = blockIdx.x * 256 + threadIdx.x;
  int base = i * 4;
  int b = base >> 10, h = base & 1023;
  int s0 = slotmap[b * 2], s1 = slotmap[b * 2 + 1];
  float w0 = wmap[b * 2], w1 = wmap[b * 2 + 1];
  ushort4v c0 = *(const ushort4v*)(buf2 + (size_t)s0 * HDIM + h);
  ushort4v c1 = *(const ushort4v*)(buf2 + (size_t)s1 * HDIM + h);
  float4v o;
#pragma unroll
  for (int j = 0; j < 4; j++) o[j] = w0 * bf2f(c0[j]) + w1 * bf2f(c1[j]);
  *(float4v*)(out + base) = o;
}

extern "C" void kernel_launch(void* const* d_in, const int* in_sizes, int n_in,
                              void* d_out, int out_size, void* d_ws, size_t ws_size,
                              hipStream_t stream) {
  const float* x     = (const float*)d_in[0];
  const float* noise = (const float*)d_in[1];
  const float* Wr    = (const float*)d_in[2];
  const float* br    = (const float*)d_in[3];
  const float* W_in  = (const float*)d_in[4];
  const float* b_in  = (const float*)d_in[5];
  const float* W_out = (const float*)d_in[6];
  const float* b_out = (const float*)d_in[7];
  float* out = (float*)d_out;
  char* ws = (char*)d_ws;

  // Aliasing via stream order: W_out_t overwrites W_in_t after gemm1a;
  // buf2 overwrites x_g after gemm1a.
  unsigned short* W_in_t  = (unsigned short*)ws;                      // 128 MB
  unsigned short* W_out_t = W_in_t;                                   // 64 MB (after gemm1)
  unsigned short* x_g     = (unsigned short*)(ws + 134217728);        // 16 MB
  unsigned short* buf2    = x_g;                                      // (after gemm1)
  unsigned short* a_buf   = (unsigned short*)(ws + 150994944);        // 64 MB
  int* meta    = (int*)(ws + 218103808);
  int* idxmap  = meta + META_INTS;
  int* slotmap = idxmap + NSLOT;
  float* wmap  = (float*)(slotmap + NSLOT);

  hipLaunchKernelGGL(router_kernel, dim3(B_TOK / 4), dim3(256), 0, stream,
                     x, noise, Wr, br, idxmap, wmap);
  hipLaunchKernelGGL(rank_kernel, dim3(1), dim3(1024), 0, stream,
                     idxmap, slotmap, meta);
  hipLaunchKernelGGL(place_kernel, dim3(B_TOK / 2), dim3(256), 0, stream,
                     x, slotmap, x_g);
  hipLaunchKernelGGL(prep_win_kernel, dim3(128, 16, 8), dim3(256), 0, stream,
                     W_in, W_in_t);
  hipLaunchKernelGGL(gemm1a_kernel, dim3(8 * MAX_T128 * 4), dim3(256), 0, stream,
                     x_g, W_in_t, b_in, a_buf, meta);
  hipLaunchKernelGGL(prep_wout_kernel, dim3(16, 64, 8), dim3(256), 0, stream,
                     W_out, W_out_t);
  hipLaunchKernelGGL(gemm2a_kernel, dim3(8 * MAX_T128), dim3(256), 0, stream,
                     a_buf, W_out_t, b_out, buf2, meta);
  hipLaunchKernelGGL(combine_kernel, dim3((B_TOK * HDIM / 4) / 256), dim3(256), 0, stream,
                     buf2, slotmap, wmap, out);
}

// Round 9
// 404.381 us; speedup vs baseline: 1.1322x; 1.1322x over previous
//
#include <hip/hip_runtime.h>

// Problem constants
#define B_TOK 4096
#define HDIM 1024
#define IDIM 4096
#define NSLOT 8192          // B_TOK * TOP_K
#define MAX_T128 72         // 128-row tiles: 64 + 7 = 71 max, +1 spare
#define G1_BLOCKS (8 * MAX_T128 * 8)   // 4608 gemm1 blocks (8 XCD x 8 J x 72 t)

using short8   = __attribute__((ext_vector_type(8))) short;
using bf16x8   = __attribute__((ext_vector_type(8))) __bf16;
using f32x4    = __attribute__((ext_vector_type(4))) float;
using int4v    = __attribute__((ext_vector_type(4))) int;
using ushort4v = __attribute__((ext_vector_type(4))) unsigned short;
using float4v  = __attribute__((ext_vector_type(4))) float;

// meta layout (ints) — 128-granular tile table
#define MC_NT128   0
#define MC_E128    8      // 72 entries
#define MC_M0128   80     // 72
#define MC_RW128   152    // 72
#define META_INTS  256

__device__ __forceinline__ unsigned short f2bf(float f) {
  unsigned u = __float_as_uint(f);
  u += 0x7FFFu + ((u >> 16) & 1u);   // RNE
  return (unsigned short)(u >> 16);
}
__device__ __forceinline__ float bf2f(unsigned short h) {
  return __uint_as_float(((unsigned)h) << 16);
}
__device__ __forceinline__ f32x4 mfma_bf16(short8 a, short8 b, f32x4 c) {
  return __builtin_amdgcn_mfma_f32_16x16x32_bf16(
      __builtin_bit_cast(bf16x8, a), __builtin_bit_cast(bf16x8, b), c, 0, 0, 0);
}
__device__ __forceinline__ void gload16(const unsigned short* g, unsigned short* l) {
  __builtin_amdgcn_global_load_lds(
      (const __attribute__((address_space(1))) unsigned int*)g,
      (__attribute__((address_space(3))) unsigned int*)l, 16, 0, 0);
}

// W_out fp32 [8][4096][1024] -> W_out_t bf16 [e][n=1024][k=4096]; T = 64*72 scratch
__device__ __forceinline__ void prep_wout_body(
    const float* __restrict__ W_out, unsigned short* __restrict__ Wt,
    int bx, int by, int e, unsigned short* T, int tid) {
  int k0 = by * 64, n0 = bx * 64;
#pragma unroll
  for (int i = 0; i < 4; i++) {
    int q = i * 256 + tid;
    int kr = q >> 4, nc = (q & 15) * 4;
    float4v v = *(const float4v*)(W_out + ((size_t)e * 4096 + k0 + kr) * 1024 + n0 + nc);
#pragma unroll
    for (int j = 0; j < 4; j++) T[(nc + j) * 72 + kr] = f2bf(v[j]);
  }
  __syncthreads();
  unsigned short* ob = Wt + ((size_t)e * 1024 + n0) * 4096;
#pragma unroll
  for (int i = 0; i < 2; i++) {
    int q = i * 256 + tid;
    int nr = q >> 3, kc = (q & 7) * 8;
    *(int4v*)(ob + (size_t)nr * 4096 + k0 + kc) = *(const int4v*)&T[nr * 72 + kc];
  }
}

// ---- Fused pre-pass: router (blocks 0..1023) + prep_win (blocks 1024..17407).
// Independent outputs; router's latency hides under prep_win's BW time.
__global__ __launch_bounds__(256) void fused_pre_kernel(
    const float* __restrict__ x, const float* __restrict__ noise,
    const float* __restrict__ Wr, const float* __restrict__ br,
    int* __restrict__ idxmap, float* __restrict__ wmap,
    const float* __restrict__ W_in, unsigned short* __restrict__ Wt) {
  __shared__ __align__(16) unsigned short T[64 * 72];
  int bid = blockIdx.x;
  int tid = threadIdx.x;
  if (bid < 1024) {
    // ---- router: logits = x@Wr + br + noise; top-2; softmax-of-2 ----
    int tok = bid * 4 + (tid >> 6);
    int l = tid & 63;
    const float* xr = x + (size_t)tok * HDIM;
    float acc[8];
#pragma unroll
    for (int e = 0; e < 8; e++) acc[e] = 0.f;
    for (int hb = 0; hb < HDIM; hb += 256) {
      int h = hb + l * 4;
      float4v xv = *(const float4v*)(xr + h);
#pragma unroll
      for (int j = 0; j < 4; j++) {
        float4v w0 = *(const float4v*)(Wr + (size_t)(h + j) * 8);
        float4v w1 = *(const float4v*)(Wr + (size_t)(h + j) * 8 + 4);
        acc[0] += xv[j] * w0[0]; acc[1] += xv[j] * w0[1];
        acc[2] += xv[j] * w0[2]; acc[3] += xv[j] * w0[3];
        acc[4] += xv[j] * w1[0]; acc[5] += xv[j] * w1[1];
        acc[6] += xv[j] * w1[2]; acc[7] += xv[j] * w1[3];
      }
    }
#pragma unroll
    for (int off = 32; off > 0; off >>= 1) {
#pragma unroll
      for (int e = 0; e < 8; e++) acc[e] += __shfl_xor(acc[e], off, 64);
    }
    if (l == 0) {
      float y[8];
#pragma unroll
      for (int e = 0; e < 8; e++) y[e] = acc[e] + br[e] + noise[(size_t)tok * 8 + e];
      int e0 = 0;
#pragma unroll
      for (int e = 1; e < 8; e++) if (y[e] > y[e0]) e0 = e;   // ties -> lower idx
      int e1 = (e0 == 0) ? 1 : 0;
#pragma unroll
      for (int e = 0; e < 8; e++) if (e != e0 && y[e] > y[e1]) e1 = e;
      float w0 = 1.f / (1.f + __expf(y[e1] - y[e0]));          // softmax of 2
      idxmap[tok * 2] = e0; idxmap[tok * 2 + 1] = e1;
      wmap[tok * 2] = w0;   wmap[tok * 2 + 1] = 1.f - w0;
    }
    return;
  }
  // ---- prep_win: W_in fp32 [8][1024][8192] -> bf16 panels [e][J(64)][128][1024]
  // panel row pr = (j>>4)*32 + half*16 + (j&15)  (x1/x2 16-col interleave)
  int pid = bid - 1024;
  int e = pid >> 11, rem = pid & 2047;
  int k0 = (rem >> 7) * 64, n0 = (rem & 127) * 64;
#pragma unroll
  for (int i = 0; i < 4; i++) {
    int q = i * 256 + tid;
    int kr = q >> 4, nc = (q & 15) * 4;
    float4v v = *(const float4v*)(W_in + ((size_t)e * 1024 + k0 + kr) * 8192 + n0 + nc);
#pragma unroll
    for (int j = 0; j < 4; j++) T[(nc + j) * 72 + kr] = f2bf(v[j]);
  }
  __syncthreads();
  int half = (n0 >= 4096) ? 1 : 0;
  int j0 = n0 - half * 4096;
  int J = j0 >> 6;
  unsigned short* ob = Wt + (((size_t)e * 64 + J) << 17);   // 128x1024 panel
#pragma unroll
  for (int i = 0; i < 2; i++) {
    int q = i * 256 + tid;
    int nr = q >> 3, kc = (q & 7) * 8;
    int pr = (nr >> 4) * 32 + half * 16 + (nr & 15);
    *(int4v*)(ob + (size_t)pr * 1024 + k0 + kc) = *(const int4v*)&T[nr * 72 + kc];
  }
}

// Deterministic slot ranks via packed prefix scan; builds 128-row tile table.
__global__ __launch_bounds__(1024) void rank_kernel(
    const int* __restrict__ idxmap, int* __restrict__ slotmap,
    int* __restrict__ meta) {
  int tid = threadIdx.x, lane = tid & 63, wv = tid >> 6;
  __shared__ unsigned wtot[16][4];
  __shared__ unsigned woff[16][4];
  __shared__ unsigned offE[8];

  int es[8];
  unsigned p0 = 0, p1 = 0, p2 = 0, p3 = 0;
#pragma unroll
  for (int j = 0; j < 8; j++) {
    int e = idxmap[tid * 8 + j];
    es[j] = e;
    unsigned c = 1u << ((e & 1) * 16);
    if (e < 2) p0 += c; else if (e < 4) p1 += c;
    else if (e < 6) p2 += c; else p3 += c;
  }
  unsigned i0 = p0, i1 = p1, i2 = p2, i3 = p3;
#pragma unroll
  for (int d = 1; d < 64; d <<= 1) {
    unsigned t0 = __shfl_up(i0, d, 64), t1 = __shfl_up(i1, d, 64);
    unsigned t2 = __shfl_up(i2, d, 64), t3 = __shfl_up(i3, d, 64);
    if (lane >= d) { i0 += t0; i1 += t1; i2 += t2; i3 += t3; }
  }
  if (lane == 63) { wtot[wv][0] = i0; wtot[wv][1] = i1; wtot[wv][2] = i2; wtot[wv][3] = i3; }
  __syncthreads();
  if (wv == 0 && lane < 16) {
    unsigned a0 = wtot[lane][0], a1 = wtot[lane][1], a2 = wtot[lane][2], a3 = wtot[lane][3];
    unsigned s0 = a0, s1 = a1, s2 = a2, s3 = a3;
#pragma unroll
    for (int d = 1; d < 16; d <<= 1) {
      unsigned t0 = __shfl_up(s0, d, 64), t1 = __shfl_up(s1, d, 64);
      unsigned t2 = __shfl_up(s2, d, 64), t3 = __shfl_up(s3, d, 64);
      if (lane >= d) { s0 += t0; s1 += t1; s2 += t2; s3 += t3; }
    }
    woff[lane][0] = s0 - a0; woff[lane][1] = s1 - a1;
    woff[lane][2] = s2 - a2; woff[lane][3] = s3 - a3;
    if (lane == 15) {
      unsigned t[8];
      t[0] = s0 & 0xFFFF; t[1] = s0 >> 16; t[2] = s1 & 0xFFFF; t[3] = s1 >> 16;
      t[4] = s2 & 0xFFFF; t[5] = s2 >> 16; t[6] = s3 & 0xFFFF; t[7] = s3 >> 16;
      unsigned off = 0; int tc = 0;
      for (int e = 0; e < 8; e++) {
        offE[e] = off;
        for (unsigned i = 0; i < t[e]; i += 128) {
          meta[MC_E128 + tc] = e;
          meta[MC_M0128 + tc] = (int)(off + i);
          meta[MC_RW128 + tc] = (int)((t[e] - i < 128u) ? (t[e] - i) : 128u);
          tc++;
        }
        off += t[e];
      }
      meta[MC_NT128] = tc;
    }
  }
  __syncthreads();
  unsigned e0w = i0 - p0 + woff[wv][0];
  unsigned e1w = i1 - p1 + woff[wv][1];
  unsigned e2w = i2 - p2 + woff[wv][2];
  unsigned e3w = i3 - p3 + woff[wv][3];
#pragma unroll
  for (int j = 0; j < 8; j++) {
    int e = es[j];
    unsigned sh = (unsigned)(e & 1) * 16;
    unsigned c = 1u << sh, v;
    if (e < 2)      { v = (e0w >> sh) & 0xFFFF; e0w += c; }
    else if (e < 4) { v = (e1w >> sh) & 0xFFFF; e1w += c; }
    else if (e < 6) { v = (e2w >> sh) & 0xFFFF; e2w += c; }
    else            { v = (e3w >> sh) & 0xFFFF; e3w += c; }
    slotmap[tid * 8 + j] = (int)(offE[e] + v);
  }
}

// Pure scatter-gather: x row (fp32) -> bf16 to both slots.
__global__ __launch_bounds__(256) void place_kernel(
    const float* __restrict__ x, const int* __restrict__ slotmap,
    unsigned short* __restrict__ x_g) {
  int tok = blockIdx.x * 2 + (threadIdx.x >> 7);
  int h = (threadIdx.x & 127) * 8;
  const float* xr = x + (size_t)tok * HDIM + h;
  float4v v0 = *(const float4v*)xr;
  float4v v1 = *(const float4v*)(xr + 4);
  int4v p;
  p[0] = (int)((unsigned)f2bf(v0[0]) | ((unsigned)f2bf(v0[1]) << 16));
  p[1] = (int)((unsigned)f2bf(v0[2]) | ((unsigned)f2bf(v0[3]) << 16));
  p[2] = (int)((unsigned)f2bf(v1[0]) | ((unsigned)f2bf(v1[1]) << 16));
  p[3] = (int)((unsigned)f2bf(v1[2]) | ((unsigned)f2bf(v1[3]) << 16));
  int s0 = slotmap[tok * 2], s1 = slotmap[tok * 2 + 1];
  *(int4v*)(x_g + (size_t)s0 * HDIM + h) = p;
  *(int4v*)(x_g + (size_t)s1 * HDIM + h) = p;
}

// Standalone prep_wout (small-ws serial path; aliased W_out_t).
__global__ __launch_bounds__(256) void prep_wout_kernel(
    const float* __restrict__ W_out, unsigned short* __restrict__ Wt) {
  __shared__ __align__(16) unsigned short T[64 * 72];
  prep_wout_body(W_out, Wt, blockIdx.x, blockIdx.y, blockIdx.z, T, threadIdx.x);
}

// ---- GEMM1 (r7-exact core): 128x128 tile, BK=64, 4 waves (2Mx2N), 2-phase
// __syncthreads loop, XCD J-banding, 32 KB LDS. Blocks >= G1_BLOCKS run
// prep_wout (big-ws co-launch path; As reused as transpose scratch).
__global__ __launch_bounds__(256, 4) void gemm1a_kernel(
    const unsigned short* __restrict__ x_g, const unsigned short* __restrict__ Wt,
    const float* __restrict__ b_in, unsigned short* __restrict__ a_buf,
    const int* __restrict__ meta,
    const float* __restrict__ W_out, unsigned short* __restrict__ Wot) {
  __shared__ __align__(16) unsigned short As[128 * 64];   // 16 KB
  __shared__ __align__(16) unsigned short Bs[128 * 64];   // 16 KB
  int bid = blockIdx.x;
  if (bid >= G1_BLOCKS) {
    int pid = bid - G1_BLOCKS;                // 0..8191
    int e = pid >> 10, rem = pid & 1023;
    prep_wout_body(W_out, Wot, rem & 15, rem >> 4, e, As, threadIdx.x);
    return;
  }
  int xcd = bid & 7, local = bid >> 3;
  int t = local >> 3;                         // t-major within XCD chunk
  if (t >= meta[MC_NT128]) return;
  int J = xcd * 8 + (local & 7);              // per-XCD J-band of 8 panels (2 MB)
  int e = meta[MC_E128 + t];
  int m0 = meta[MC_M0128 + t];
  int rows = meta[MC_RW128 + t];
  const unsigned short* Wp = Wt + (((size_t)e * 64 + J) << 17);

  int tid = threadIdx.x, l = tid & 63, w = tid >> 6;
  int g = l >> 4, ln = l & 15, lr = l >> 3;
  int uc = (l & 7) ^ lr;                      // pre-swizzled source 16B-unit
  int wm = w >> 1, wn = w & 1;

  const unsigned short* sA[4]; const unsigned short* sB[4]; int dO[4];
#pragma unroll
  for (int i = 0; i < 4; i++) {
    int c = w * 4 + i;                        // chunk 0..15 (8 rows each)
    int r = c * 8 + lr;
    int ra = r < rows ? r : rows - 1;
    sA[i] = x_g + (size_t)(m0 + ra) * HDIM + uc * 8;
    sB[i] = Wp + (size_t)r * 1024 + uc * 8;
    dO[i] = c * 512 + l * 8;
  }

  f32x4 acc[4][4];
#pragma unroll
  for (int mf = 0; mf < 4; mf++)
#pragma unroll
    for (int nf = 0; nf < 4; nf++) acc[mf][nf] = (f32x4){0.f, 0.f, 0.f, 0.f};

#pragma unroll 1
  for (int kt = 0; kt < 16; kt++) {
#pragma unroll
    for (int i = 0; i < 4; i++) gload16(sA[i] + kt * 64, &As[dO[i]]);
#pragma unroll
    for (int i = 0; i < 4; i++) gload16(sB[i] + kt * 64, &Bs[dO[i]]);
    __syncthreads();
#pragma unroll
    for (int ks = 0; ks < 2; ks++) {
      int u0 = (((ks * 4 + g) ^ (ln & 7)) << 3);
      short8 af[4], bfr[4];
#pragma unroll
      for (int mf = 0; mf < 4; mf++)
        af[mf] = *(const short8*)&As[(wm * 64 + mf * 16 + ln) * 64 + u0];
#pragma unroll
      for (int nf = 0; nf < 4; nf++)
        bfr[nf] = *(const short8*)&Bs[(wn * 64 + nf * 16 + ln) * 64 + u0];
#pragma unroll
      for (int mf = 0; mf < 4; mf++)
#pragma unroll
        for (int nf = 0; nf < 4; nf++)
          acc[mf][nf] = mfma_bf16(af[mf], bfr[nf], acc[mf][nf]);
    }
    __syncthreads();
  }
  // fused bias + SwiGLU: frag pair (2np, 2np+1) = (x1, x2) of same j
#pragma unroll
  for (int mf = 0; mf < 4; mf++) {
#pragma unroll
    for (int np = 0; np < 2; np++) {
      int j = J * 64 + wn * 32 + np * 16 + ln;
      float b1 = b_in[(size_t)e * 8192 + j];
      float b2 = b_in[(size_t)e * 8192 + 4096 + j];
#pragma unroll
      for (int r = 0; r < 4; r++) {
        int m = wm * 64 + mf * 16 + g * 4 + r;
        if (m < rows) {
          float h1 = acc[mf][np * 2][r] + b1;
          float h2 = acc[mf][np * 2 + 1][r] + b2;
          a_buf[(size_t)(m0 + m) * IDIM + j] = f2bf(h1 / (1.f + __expf(-h2)));
        }
      }
    }
  }
}

// ---- GEMM2 (r8-exact): 128m x 128n tile, K=4096, 4 waves (2Mx2N), 2-phase,
// n-band = xcd; grid 8*MAX_T128 = 576.
__global__ __launch_bounds__(256, 4) void gemm2a_kernel(
    const unsigned short* __restrict__ a_buf, const unsigned short* __restrict__ Wt,
    const float* __restrict__ b_out, unsigned short* __restrict__ buf2,
    const int* __restrict__ meta) {
  int bid = blockIdx.x;
  int xcd = bid & 7;
  int t = bid >> 3;
  if (t >= meta[MC_NT128]) return;
  int n0 = xcd * 128;
  int e = meta[MC_E128 + t];
  int m0 = meta[MC_M0128 + t];
  int rows = meta[MC_RW128 + t];
  const unsigned short* Wp = Wt + ((size_t)e * 1024 + n0) * 4096;

  __shared__ __align__(16) unsigned short As[128 * 64];   // 16 KB
  __shared__ __align__(16) unsigned short Bs[128 * 64];   // 16 KB

  int tid = threadIdx.x, l = tid & 63, w = tid >> 6;
  int g = l >> 4, ln = l & 15, lr = l >> 3;
  int uc = (l & 7) ^ lr;
  int wm = w >> 1, wn = w & 1;

  const unsigned short* sA[4]; const unsigned short* sB[4]; int dO[4];
#pragma unroll
  for (int i = 0; i < 4; i++) {
    int c = w * 4 + i;                        // chunk 0..15
    int r = c * 8 + lr;
    int ra = r < rows ? r : rows - 1;
    sA[i] = a_buf + (size_t)(m0 + ra) * IDIM + uc * 8;
    sB[i] = Wp + (size_t)r * 4096 + uc * 8;
    dO[i] = c * 512 + l * 8;
  }

  f32x4 acc[4][4];
#pragma unroll
  for (int mf = 0; mf < 4; mf++)
#pragma unroll
    for (int nf = 0; nf < 4; nf++) acc[mf][nf] = (f32x4){0.f, 0.f, 0.f, 0.f};

#pragma unroll 1
  for (int kt = 0; kt < 64; kt++) {
#pragma unroll
    for (int i = 0; i < 4; i++) gload16(sA[i] + kt * 64, &As[dO[i]]);
#pragma unroll
    for (int i = 0; i < 4; i++) gload16(sB[i] + kt * 64, &Bs[dO[i]]);
    __syncthreads();
#pragma unroll
    for (int ks = 0; ks < 2; ks++) {
      int u0 = (((ks * 4 + g) ^ (ln & 7)) << 3);
      short8 af[4], bfr[4];
#pragma unroll
      for (int mf = 0; mf < 4; mf++)
        af[mf] = *(const short8*)&As[(wm * 64 + mf * 16 + ln) * 64 + u0];
#pragma unroll
      for (int nf = 0; nf < 4; nf++)
        bfr[nf] = *(const short8*)&Bs[(wn * 64 + nf * 16 + ln) * 64 + u0];
#pragma unroll
      for (int mf = 0; mf < 4; mf++)
#pragma unroll
        for (int nf = 0; nf < 4; nf++)
          acc[mf][nf] = mfma_bf16(af[mf], bfr[nf], acc[mf][nf]);
    }
    __syncthreads();
  }
#pragma unroll
  for (int mf = 0; mf < 4; mf++) {
#pragma unroll
    for (int nf = 0; nf < 4; nf++) {
      int col = n0 + wn * 64 + nf * 16 + ln;
      float bo = b_out[(size_t)e * 1024 + col];
#pragma unroll
      for (int r = 0; r < 4; r++) {
        int m = wm * 64 + mf * 16 + g * 4 + r;
        if (m < rows) {
          buf2[(size_t)(m0 + m) * HDIM + col] = f2bf(acc[mf][nf][r] + bo);
        }
      }
    }
  }
}

// out[b] = w0 * buf2[slot0] + w1 * buf2[slot1]  (fp32, deterministic order)
__global__ __launch_bounds__(256) void combine_kernel(
    const unsigned short* __restrict__ buf2, const int* __restrict__ slotmap,
    const float* __restrict__ wmap, float* __restrict__ out) {
  int i = blockIdx.x * 256 + threadIdx.x;
  int base = i * 4;
  int b = base >> 10, h = base & 1023;
  int s0 = slotmap[b * 2], s1 = slotmap[b * 2 + 1];
  float w0 = wmap[b * 2], w1 = wmap[b * 2 + 1];
  ushort4v c0 = *(const ushort4v*)(buf2 + (size_t)s0 * HDIM + h);
  ushort4v c1 = *(const ushort4v*)(buf2 + (size_t)s1 * HDIM + h);
  float4v o;
#pragma unroll
  for (int j = 0; j < 4; j++) o[j] = w0 * bf2f(c0[j]) + w1 * bf2f(c1[j]);
  *(float4v*)(out + base) = o;
}

extern "C" void kernel_launch(void* const* d_in, const int* in_sizes, int n_in,
                              void* d_out, int out_size, void* d_ws, size_t ws_size,
                              hipStream_t stream) {
  const float* x     = (const float*)d_in[0];
  const float* noise = (const float*)d_in[1];
  const float* Wr    = (const float*)d_in[2];
  const float* br    = (const float*)d_in[3];
  const float* W_in  = (const float*)d_in[4];
  const float* b_in  = (const float*)d_in[5];
  const float* W_out = (const float*)d_in[6];
  const float* b_out = (const float*)d_in[7];
  float* out = (float*)d_out;
  char* ws = (char*)d_ws;

  // Layout: W_in_t [0,128M); x_g [128M,144M); a_buf [144M,208M).
  // Small ws: W_out_t aliases W_in_t (serial prep_wout after gemm1a);
  //           buf2 aliases x_g; meta at 218103808.
  // Big ws (>= NEED_B): W_out_t separate at 218103808 -> prep_wout co-launched
  //           inside gemm1a's grid; meta at 285212672.
  const size_t NEED_B = 285343744ULL;
  bool big = (ws_size >= NEED_B);

  unsigned short* W_in_t  = (unsigned short*)ws;                      // 128 MB
  unsigned short* x_g     = (unsigned short*)(ws + 134217728);        // 16 MB
  unsigned short* buf2    = x_g;                                      // after gemm1
  unsigned short* a_buf   = (unsigned short*)(ws + 150994944);        // 64 MB
  unsigned short* W_out_t = big ? (unsigned short*)(ws + 218103808)   // 64 MB
                                : W_in_t;                             // aliased
  int* meta    = (int*)(ws + (big ? 285212672 : 218103808));
  int* idxmap  = meta + META_INTS;
  int* slotmap = idxmap + NSLOT;
  float* wmap  = (float*)(slotmap + NSLOT);

  hipLaunchKernelGGL(fused_pre_kernel, dim3(1024 + 16384), dim3(256), 0, stream,
                     x, noise, Wr, br, idxmap, wmap, W_in, W_in_t);
  hipLaunchKernelGGL(rank_kernel, dim3(1), dim3(1024), 0, stream,
                     idxmap, slotmap, meta);
  hipLaunchKernelGGL(place_kernel, dim3(B_TOK / 2), dim3(256), 0, stream,
                     x, slotmap, x_g);
  hipLaunchKernelGGL(gemm1a_kernel,
                     dim3(big ? (G1_BLOCKS + 8192) : G1_BLOCKS), dim3(256), 0, stream,
                     x_g, W_in_t, b_in, a_buf, meta, W_out, W_out_t);
  if (!big) {
    hipLaunchKernelGGL(prep_wout_kernel, dim3(16, 64, 8), dim3(256), 0, stream,
                       W_out, W_out_t);
  }
  hipLaunchKernelGGL(gemm2a_kernel, dim3(8 * MAX_T128), dim3(256), 0, stream,
                     a_buf, W_out_t, b_out, buf2, meta);
  hipLaunchKernelGGL(combine_kernel, dim3((B_TOK * HDIM / 4) / 256), dim3(256), 0, stream,
                     buf2, slotmap, wmap, out);
}

// Round 10
// 401.690 us; speedup vs baseline: 1.1398x; 1.0067x over previous
//
#include <hip/hip_runtime.h>

// Problem constants
#define B_TOK 4096
#define HDIM 1024
#define IDIM 4096
#define NSLOT 8192          // B_TOK * TOP_K
#define MAX_T128 72         // 128-row tiles: 64 + 7 = 71 max, +1 spare
#define G1_BLOCKS (8 * MAX_T128 * 8)   // 4608 gemm1 blocks (8 XCD x 8 J x 72 t)

using short8   = __attribute__((ext_vector_type(8))) short;
using bf16x8   = __attribute__((ext_vector_type(8))) __bf16;
using f32x4    = __attribute__((ext_vector_type(4))) float;
using int4v    = __attribute__((ext_vector_type(4))) int;
using ushort4v = __attribute__((ext_vector_type(4))) unsigned short;
using float4v  = __attribute__((ext_vector_type(4))) float;

// meta layout (ints) — 128-granular tile table
#define MC_NT128   0
#define MC_E128    8      // 72 entries
#define MC_M0128   80     // 72
#define MC_RW128   152    // 72
#define META_INTS  256

__device__ __forceinline__ unsigned short f2bf(float f) {
  unsigned u = __float_as_uint(f);
  u += 0x7FFFu + ((u >> 16) & 1u);   // RNE
  return (unsigned short)(u >> 16);
}
__device__ __forceinline__ float bf2f(unsigned short h) {
  return __uint_as_float(((unsigned)h) << 16);
}
__device__ __forceinline__ f32x4 mfma_bf16(short8 a, short8 b, f32x4 c) {
  return __builtin_amdgcn_mfma_f32_16x16x32_bf16(
      __builtin_bit_cast(bf16x8, a), __builtin_bit_cast(bf16x8, b), c, 0, 0, 0);
}
__device__ __forceinline__ void gload16(const unsigned short* g, unsigned short* l) {
  __builtin_amdgcn_global_load_lds(
      (const __attribute__((address_space(1))) unsigned int*)g,
      (__attribute__((address_space(3))) unsigned int*)l, 16, 0, 0);
}

// W_out fp32 [8][4096][1024] -> W_out_t bf16 [e][n=1024][k=4096]; T = 64*72 scratch
__device__ __forceinline__ void prep_wout_body(
    const float* __restrict__ W_out, unsigned short* __restrict__ Wt,
    int bx, int by, int e, unsigned short* T, int tid) {
  int k0 = by * 64, n0 = bx * 64;
#pragma unroll
  for (int i = 0; i < 4; i++) {
    int q = i * 256 + tid;
    int kr = q >> 4, nc = (q & 15) * 4;
    float4v v = *(const float4v*)(W_out + ((size_t)e * 4096 + k0 + kr) * 1024 + n0 + nc);
#pragma unroll
    for (int j = 0; j < 4; j++) T[(nc + j) * 72 + kr] = f2bf(v[j]);
  }
  __syncthreads();
  unsigned short* ob = Wt + ((size_t)e * 1024 + n0) * 4096;
#pragma unroll
  for (int i = 0; i < 2; i++) {
    int q = i * 256 + tid;
    int nr = q >> 3, kc = (q & 7) * 8;
    *(int4v*)(ob + (size_t)nr * 4096 + k0 + kc) = *(const int4v*)&T[nr * 72 + kc];
  }
}

// ---- Fused pre-pass: router (0..1023) + prep_win (1024..17407) + x->bf16
// convert (17408..19455). All independent; latency hides under BW time.
__global__ __launch_bounds__(256) void fused_pre_kernel(
    const float* __restrict__ x, const float* __restrict__ noise,
    const float* __restrict__ Wr, const float* __restrict__ br,
    int* __restrict__ idxmap, float* __restrict__ wmap,
    const float* __restrict__ W_in, unsigned short* __restrict__ Wt,
    unsigned short* __restrict__ x_bf) {
  __shared__ __align__(16) unsigned short T[64 * 72];
  int bid = blockIdx.x;
  int tid = threadIdx.x;
  if (bid < 1024) {
    // ---- router: logits = x@Wr + br + noise; top-2; softmax-of-2 ----
    int tok = bid * 4 + (tid >> 6);
    int l = tid & 63;
    const float* xr = x + (size_t)tok * HDIM;
    float acc[8];
#pragma unroll
    for (int e = 0; e < 8; e++) acc[e] = 0.f;
    for (int hb = 0; hb < HDIM; hb += 256) {
      int h = hb + l * 4;
      float4v xv = *(const float4v*)(xr + h);
#pragma unroll
      for (int j = 0; j < 4; j++) {
        float4v w0 = *(const float4v*)(Wr + (size_t)(h + j) * 8);
        float4v w1 = *(const float4v*)(Wr + (size_t)(h + j) * 8 + 4);
        acc[0] += xv[j] * w0[0]; acc[1] += xv[j] * w0[1];
        acc[2] += xv[j] * w0[2]; acc[3] += xv[j] * w0[3];
        acc[4] += xv[j] * w1[0]; acc[5] += xv[j] * w1[1];
        acc[6] += xv[j] * w1[2]; acc[7] += xv[j] * w1[3];
      }
    }
#pragma unroll
    for (int off = 32; off > 0; off >>= 1) {
#pragma unroll
      for (int e = 0; e < 8; e++) acc[e] += __shfl_xor(acc[e], off, 64);
    }
    if (l == 0) {
      float y[8];
#pragma unroll
      for (int e = 0; e < 8; e++) y[e] = acc[e] + br[e] + noise[(size_t)tok * 8 + e];
      int e0 = 0;
#pragma unroll
      for (int e = 1; e < 8; e++) if (y[e] > y[e0]) e0 = e;   // ties -> lower idx
      int e1 = (e0 == 0) ? 1 : 0;
#pragma unroll
      for (int e = 0; e < 8; e++) if (e != e0 && y[e] > y[e1]) e1 = e;
      float w0 = 1.f / (1.f + __expf(y[e1] - y[e0]));          // softmax of 2
      idxmap[tok * 2] = e0; idxmap[tok * 2 + 1] = e1;
      wmap[tok * 2] = w0;   wmap[tok * 2 + 1] = 1.f - w0;
    }
    return;
  }
  if (bid >= 17408) {
    // ---- x fp32 -> bf16, row-major (unsorted; gemm1 gathers via inv_slotmap)
    int flat = (bid - 17408) * 2048 + tid * 8;
    float4v v0 = *(const float4v*)(x + flat);
    float4v v1 = *(const float4v*)(x + flat + 4);
    int4v p;
    p[0] = (int)((unsigned)f2bf(v0[0]) | ((unsigned)f2bf(v0[1]) << 16));
    p[1] = (int)((unsigned)f2bf(v0[2]) | ((unsigned)f2bf(v0[3]) << 16));
    p[2] = (int)((unsigned)f2bf(v1[0]) | ((unsigned)f2bf(v1[1]) << 16));
    p[3] = (int)((unsigned)f2bf(v1[2]) | ((unsigned)f2bf(v1[3]) << 16));
    *(int4v*)(x_bf + flat) = p;
    return;
  }
  // ---- prep_win: W_in fp32 [8][1024][8192] -> bf16 panels [e][J(64)][128][1024]
  // panel row pr = (j>>4)*32 + half*16 + (j&15)  (x1/x2 16-col interleave)
  int pid = bid - 1024;
  int e = pid >> 11, rem = pid & 2047;
  int k0 = (rem >> 7) * 64, n0 = (rem & 127) * 64;
#pragma unroll
  for (int i = 0; i < 4; i++) {
    int q = i * 256 + tid;
    int kr = q >> 4, nc = (q & 15) * 4;
    float4v v = *(const float4v*)(W_in + ((size_t)e * 1024 + k0 + kr) * 8192 + n0 + nc);
#pragma unroll
    for (int j = 0; j < 4; j++) T[(nc + j) * 72 + kr] = f2bf(v[j]);
  }
  __syncthreads();
  int half = (n0 >= 4096) ? 1 : 0;
  int j0 = n0 - half * 4096;
  int J = j0 >> 6;
  unsigned short* ob = Wt + (((size_t)e * 64 + J) << 17);   // 128x1024 panel
#pragma unroll
  for (int i = 0; i < 2; i++) {
    int q = i * 256 + tid;
    int nr = q >> 3, kc = (q & 7) * 8;
    int pr = (nr >> 4) * 32 + half * 16 + (nr & 15);
    *(int4v*)(ob + (size_t)pr * 1024 + k0 + kc) = *(const int4v*)&T[nr * 72 + kc];
  }
}

// Deterministic slot ranks via packed prefix scan; builds 128-row tile table
// and inv_slotmap (slot -> token). inv may alias idxmap: all idxmap reads
// complete before the __syncthreads that precedes the write loop.
__global__ __launch_bounds__(1024) void rank_kernel(
    const int* __restrict__ idxmap, int* __restrict__ slotmap,
    int* __restrict__ meta, int* __restrict__ inv) {
  int tid = threadIdx.x, lane = tid & 63, wv = tid >> 6;
  __shared__ unsigned wtot[16][4];
  __shared__ unsigned woff[16][4];
  __shared__ unsigned offE[8];

  int es[8];
  unsigned p0 = 0, p1 = 0, p2 = 0, p3 = 0;
#pragma unroll
  for (int j = 0; j < 8; j++) {
    int e = idxmap[tid * 8 + j];
    es[j] = e;
    unsigned c = 1u << ((e & 1) * 16);
    if (e < 2) p0 += c; else if (e < 4) p1 += c;
    else if (e < 6) p2 += c; else p3 += c;
  }
  unsigned i0 = p0, i1 = p1, i2 = p2, i3 = p3;
#pragma unroll
  for (int d = 1; d < 64; d <<= 1) {
    unsigned t0 = __shfl_up(i0, d, 64), t1 = __shfl_up(i1, d, 64);
    unsigned t2 = __shfl_up(i2, d, 64), t3 = __shfl_up(i3, d, 64);
    if (lane >= d) { i0 += t0; i1 += t1; i2 += t2; i3 += t3; }
  }
  if (lane == 63) { wtot[wv][0] = i0; wtot[wv][1] = i1; wtot[wv][2] = i2; wtot[wv][3] = i3; }
  __syncthreads();
  if (wv == 0 && lane < 16) {
    unsigned a0 = wtot[lane][0], a1 = wtot[lane][1], a2 = wtot[lane][2], a3 = wtot[lane][3];
    unsigned s0 = a0, s1 = a1, s2 = a2, s3 = a3;
#pragma unroll
    for (int d = 1; d < 16; d <<= 1) {
      unsigned t0 = __shfl_up(s0, d, 64), t1 = __shfl_up(s1, d, 64);
      unsigned t2 = __shfl_up(s2, d, 64), t3 = __shfl_up(s3, d, 64);
      if (lane >= d) { s0 += t0; s1 += t1; s2 += t2; s3 += t3; }
    }
    woff[lane][0] = s0 - a0; woff[lane][1] = s1 - a1;
    woff[lane][2] = s2 - a2; woff[lane][3] = s3 - a3;
    if (lane == 15) {
      unsigned t[8];
      t[0] = s0 & 0xFFFF; t[1] = s0 >> 16; t[2] = s1 & 0xFFFF; t[3] = s1 >> 16;
      t[4] = s2 & 0xFFFF; t[5] = s2 >> 16; t[6] = s3 & 0xFFFF; t[7] = s3 >> 16;
      unsigned off = 0; int tc = 0;
      for (int e = 0; e < 8; e++) {
        offE[e] = off;
        for (unsigned i = 0; i < t[e]; i += 128) {
          meta[MC_E128 + tc] = e;
          meta[MC_M0128 + tc] = (int)(off + i);
          meta[MC_RW128 + tc] = (int)((t[e] - i < 128u) ? (t[e] - i) : 128u);
          tc++;
        }
        off += t[e];
      }
      meta[MC_NT128] = tc;
    }
  }
  __syncthreads();
  unsigned e0w = i0 - p0 + woff[wv][0];
  unsigned e1w = i1 - p1 + woff[wv][1];
  unsigned e2w = i2 - p2 + woff[wv][2];
  unsigned e3w = i3 - p3 + woff[wv][3];
#pragma unroll
  for (int j = 0; j < 8; j++) {
    int e = es[j];
    unsigned sh = (unsigned)(e & 1) * 16;
    unsigned c = 1u << sh, v;
    if (e < 2)      { v = (e0w >> sh) & 0xFFFF; e0w += c; }
    else if (e < 4) { v = (e1w >> sh) & 0xFFFF; e1w += c; }
    else if (e < 6) { v = (e2w >> sh) & 0xFFFF; e2w += c; }
    else            { v = (e3w >> sh) & 0xFFFF; e3w += c; }
    int slot = (int)(offE[e] + v);
    slotmap[tid * 8 + j] = slot;
    inv[slot] = (tid * 8 + j) >> 1;          // slot -> token
  }
}

// Standalone prep_wout (small-ws serial path; aliased W_out_t).
__global__ __launch_bounds__(256) void prep_wout_kernel(
    const float* __restrict__ W_out, unsigned short* __restrict__ Wt) {
  __shared__ __align__(16) unsigned short T[64 * 72];
  prep_wout_body(W_out, Wt, blockIdx.x, blockIdx.y, blockIdx.z, T, threadIdx.x);
}

// ---- GEMM1 (r7-exact core): 128x128 tile, BK=64, 4 waves (2Mx2N), 2-phase
// __syncthreads loop, XCD J-banding, 32 KB LDS. A rows gathered from x_bf via
// inv_slotmap (per-lane global_load_lds source). Blocks >= G1_BLOCKS run
// prep_wout (big-ws co-launch; As reused as transpose scratch).
__global__ __launch_bounds__(256, 4) void gemm1a_kernel(
    const unsigned short* __restrict__ x_bf, const unsigned short* __restrict__ Wt,
    const float* __restrict__ b_in, unsigned short* __restrict__ a_buf,
    const int* __restrict__ meta, const int* __restrict__ inv,
    const float* __restrict__ W_out, unsigned short* __restrict__ Wot) {
  __shared__ __align__(16) unsigned short As[128 * 64];   // 16 KB
  __shared__ __align__(16) unsigned short Bs[128 * 64];   // 16 KB
  int bid = blockIdx.x;
  if (bid >= G1_BLOCKS) {
    int pid = bid - G1_BLOCKS;                // 0..8191
    int e = pid >> 10, rem = pid & 1023;
    prep_wout_body(W_out, Wot, rem & 15, rem >> 4, e, As, threadIdx.x);
    return;
  }
  int xcd = bid & 7, local = bid >> 3;
  int t = local >> 3;                         // t-major within XCD chunk
  if (t >= meta[MC_NT128]) return;
  int J = xcd * 8 + (local & 7);              // per-XCD J-band of 8 panels (2 MB)
  int e = meta[MC_E128 + t];
  int m0 = meta[MC_M0128 + t];
  int rows = meta[MC_RW128 + t];
  const unsigned short* Wp = Wt + (((size_t)e * 64 + J) << 17);

  int tid = threadIdx.x, l = tid & 63, w = tid >> 6;
  int g = l >> 4, ln = l & 15, lr = l >> 3;
  int uc = (l & 7) ^ lr;                      // pre-swizzled source 16B-unit
  int wm = w >> 1, wn = w & 1;

  const unsigned short* sA[4]; const unsigned short* sB[4]; int dO[4];
#pragma unroll
  for (int i = 0; i < 4; i++) {
    int c = w * 4 + i;                        // chunk 0..15 (8 rows each)
    int r = c * 8 + lr;
    int ra = r < rows ? r : rows - 1;
    int tok = inv[m0 + ra];                   // slot -> token gather
    sA[i] = x_bf + (size_t)tok * HDIM + uc * 8;
    sB[i] = Wp + (size_t)r * 1024 + uc * 8;
    dO[i] = c * 512 + l * 8;
  }

  f32x4 acc[4][4];
#pragma unroll
  for (int mf = 0; mf < 4; mf++)
#pragma unroll
    for (int nf = 0; nf < 4; nf++) acc[mf][nf] = (f32x4){0.f, 0.f, 0.f, 0.f};

#pragma unroll 1
  for (int kt = 0; kt < 16; kt++) {
#pragma unroll
    for (int i = 0; i < 4; i++) gload16(sA[i] + kt * 64, &As[dO[i]]);
#pragma unroll
    for (int i = 0; i < 4; i++) gload16(sB[i] + kt * 64, &Bs[dO[i]]);
    __syncthreads();
#pragma unroll
    for (int ks = 0; ks < 2; ks++) {
      int u0 = (((ks * 4 + g) ^ (ln & 7)) << 3);
      short8 af[4], bfr[4];
#pragma unroll
      for (int mf = 0; mf < 4; mf++)
        af[mf] = *(const short8*)&As[(wm * 64 + mf * 16 + ln) * 64 + u0];
#pragma unroll
      for (int nf = 0; nf < 4; nf++)
        bfr[nf] = *(const short8*)&Bs[(wn * 64 + nf * 16 + ln) * 64 + u0];
#pragma unroll
      for (int mf = 0; mf < 4; mf++)
#pragma unroll
        for (int nf = 0; nf < 4; nf++)
          acc[mf][nf] = mfma_bf16(af[mf], bfr[nf], acc[mf][nf]);
    }
    __syncthreads();
  }
  // fused bias + SwiGLU: frag pair (2np, 2np+1) = (x1, x2) of same j
#pragma unroll
  for (int mf = 0; mf < 4; mf++) {
#pragma unroll
    for (int np = 0; np < 2; np++) {
      int j = J * 64 + wn * 32 + np * 16 + ln;
      float b1 = b_in[(size_t)e * 8192 + j];
      float b2 = b_in[(size_t)e * 8192 + 4096 + j];
#pragma unroll
      for (int r = 0; r < 4; r++) {
        int m = wm * 64 + mf * 16 + g * 4 + r;
        if (m < rows) {
          float h1 = acc[mf][np * 2][r] + b1;
          float h2 = acc[mf][np * 2 + 1][r] + b2;
          a_buf[(size_t)(m0 + m) * IDIM + j] = f2bf(h1 / (1.f + __expf(-h2)));
        }
      }
    }
  }
}

// ---- GEMM2 (r8-exact): 128m x 128n tile, K=4096, 4 waves (2Mx2N), 2-phase,
// n-band = xcd; grid 8*MAX_T128 = 576.
__global__ __launch_bounds__(256, 4) void gemm2a_kernel(
    const unsigned short* __restrict__ a_buf, const unsigned short* __restrict__ Wt,
    const float* __restrict__ b_out, unsigned short* __restrict__ buf2,
    const int* __restrict__ meta) {
  int bid = blockIdx.x;
  int xcd = bid & 7;
  int t = bid >> 3;
  if (t >= meta[MC_NT128]) return;
  int n0 = xcd * 128;
  int e = meta[MC_E128 + t];
  int m0 = meta[MC_M0128 + t];
  int rows = meta[MC_RW128 + t];
  const unsigned short* Wp = Wt + ((size_t)e * 1024 + n0) * 4096;

  __shared__ __align__(16) unsigned short As[128 * 64];   // 16 KB
  __shared__ __align__(16) unsigned short Bs[128 * 64];   // 16 KB

  int tid = threadIdx.x, l = tid & 63, w = tid >> 6;
  int g = l >> 4, ln = l & 15, lr = l >> 3;
  int uc = (l & 7) ^ lr;
  int wm = w >> 1, wn = w & 1;

  const unsigned short* sA[4]; const unsigned short* sB[4]; int dO[4];
#pragma unroll
  for (int i = 0; i < 4; i++) {
    int c = w * 4 + i;                        // chunk 0..15
    int r = c * 8 + lr;
    int ra = r < rows ? r : rows - 1;
    sA[i] = a_buf + (size_t)(m0 + ra) * IDIM + uc * 8;
    sB[i] = Wp + (size_t)r * 4096 + uc * 8;
    dO[i] = c * 512 + l * 8;
  }

  f32x4 acc[4][4];
#pragma unroll
  for (int mf = 0; mf < 4; mf++)
#pragma unroll
    for (int nf = 0; nf < 4; nf++) acc[mf][nf] = (f32x4){0.f, 0.f, 0.f, 0.f};

#pragma unroll 1
  for (int kt = 0; kt < 64; kt++) {
#pragma unroll
    for (int i = 0; i < 4; i++) gload16(sA[i] + kt * 64, &As[dO[i]]);
#pragma unroll
    for (int i = 0; i < 4; i++) gload16(sB[i] + kt * 64, &Bs[dO[i]]);
    __syncthreads();
#pragma unroll
    for (int ks = 0; ks < 2; ks++) {
      int u0 = (((ks * 4 + g) ^ (ln & 7)) << 3);
      short8 af[4], bfr[4];
#pragma unroll
      for (int mf = 0; mf < 4; mf++)
        af[mf] = *(const short8*)&As[(wm * 64 + mf * 16 + ln) * 64 + u0];
#pragma unroll
      for (int nf = 0; nf < 4; nf++)
        bfr[nf] = *(const short8*)&Bs[(wn * 64 + nf * 16 + ln) * 64 + u0];
#pragma unroll
      for (int mf = 0; mf < 4; mf++)
#pragma unroll
        for (int nf = 0; nf < 4; nf++)
          acc[mf][nf] = mfma_bf16(af[mf], bfr[nf], acc[mf][nf]);
    }
    __syncthreads();
  }
#pragma unroll
  for (int mf = 0; mf < 4; mf++) {
#pragma unroll
    for (int nf = 0; nf < 4; nf++) {
      int col = n0 + wn * 64 + nf * 16 + ln;
      float bo = b_out[(size_t)e * 1024 + col];
#pragma unroll
      for (int r = 0; r < 4; r++) {
        int m = wm * 64 + mf * 16 + g * 4 + r;
        if (m < rows) {
          buf2[(size_t)(m0 + m) * HDIM + col] = f2bf(acc[mf][nf][r] + bo);
        }
      }
    }
  }
}

// out[b] = w0 * buf2[slot0] + w1 * buf2[slot1]  (fp32, deterministic order)
__global__ __launch_bounds__(256) void combine_kernel(
    const unsigned short* __restrict__ buf2, const int* __restrict__ slotmap,
    const float* __restrict__ wmap, float* __restrict__ out) {
  int i = blockIdx.x * 256 + threadIdx.x;
  int base = i * 4;
  int b = base >> 10, h = base & 1023;
  int s0 = slotmap[b * 2], s1 = slotmap[b * 2 + 1];
  float w0 = wmap[b * 2], w1 = wmap[b * 2 + 1];
  ushort4v c0 = *(const ushort4v*)(buf2 + (size_t)s0 * HDIM + h);
  ushort4v c1 = *(const ushort4v*)(buf2 + (size_t)s1 * HDIM + h);
  float4v o;
#pragma unroll
  for (int j = 0; j < 4; j++) o[j] = w0 * bf2f(c0[j]) + w1 * bf2f(c1[j]);
  *(float4v*)(out + base) = o;
}

extern "C" void kernel_launch(void* const* d_in, const int* in_sizes, int n_in,
                              void* d_out, int out_size, void* d_ws, size_t ws_size,
                              hipStream_t stream) {
  const float* x     = (const float*)d_in[0];
  const float* noise = (const float*)d_in[1];
  const float* Wr    = (const float*)d_in[2];
  const float* br    = (const float*)d_in[3];
  const float* W_in  = (const float*)d_in[4];
  const float* b_in  = (const float*)d_in[5];
  const float* W_out = (const float*)d_in[6];
  const float* b_out = (const float*)d_in[7];
  float* out = (float*)d_out;
  char* ws = (char*)d_ws;

  // Layout: W_in_t [0,128M); x_bf [128M,136M); buf2 aliases [128M,144M)
  // (written only after gemm1a's last x_bf read — stream order); a_buf
  // [144M,208M). Big ws: W_out_t separate at 208M (prep_wout co-launched in
  // gemm1a); small ws: W_out_t aliases W_in_t, serial prep_wout.
  const size_t NEED_B = 285343744ULL;
  bool big = (ws_size >= NEED_B);

  unsigned short* W_in_t  = (unsigned short*)ws;                      // 128 MB
  unsigned short* x_bf    = (unsigned short*)(ws + 134217728);        // 8 MB
  unsigned short* buf2    = x_bf;                                     // after gemm1
  unsigned short* a_buf   = (unsigned short*)(ws + 150994944);        // 64 MB
  unsigned short* W_out_t = big ? (unsigned short*)(ws + 218103808)   // 64 MB
                                : W_in_t;                             // aliased
  int* meta    = (int*)(ws + (big ? 285212672 : 218103808));
  int* idxmap  = meta + META_INTS;
  int* slotmap = idxmap + NSLOT;
  float* wmap  = (float*)(slotmap + NSLOT);
  int* inv     = idxmap;   // idxmap is dead after rank; rank writes inv there

  hipLaunchKernelGGL(fused_pre_kernel, dim3(1024 + 16384 + 2048), dim3(256), 0, stream,
                     x, noise, Wr, br, idxmap, wmap, W_in, W_in_t, x_bf);
  hipLaunchKernelGGL(rank_kernel, dim3(1), dim3(1024), 0, stream,
                     idxmap, slotmap, meta, inv);
  hipLaunchKernelGGL(gemm1a_kernel,
                     dim3(big ? (G1_BLOCKS + 8192) : G1_BLOCKS), dim3(256), 0, stream,
                     x_bf, W_in_t, b_in, a_buf, meta, inv, W_out, W_out_t);
  if (!big) {
    hipLaunchKernelGGL(prep_wout_kernel, dim3(16, 64, 8), dim3(256), 0, stream,
                       W_out, W_out_t);
  }
  hipLaunchKernelGGL(gemm2a_kernel, dim3(8 * MAX_T128), dim3(256), 0, stream,
                     a_buf, W_out_t, b_out, buf2, meta);
  hipLaunchKernelGGL(combine_kernel, dim3((B_TOK * HDIM / 4) / 256), dim3(256), 0, stream,
                     buf2, slotmap, wmap, out);
}